// Round 9
// baseline (1044.146 us; speedup 1.0000x reference)
//
#include <hip/hip_runtime.h>
#include <hip/hip_bf16.h>
#include <stdint.h>

#define TOKENS 4096
#define DMODEL 1024
#define VOCAB  50257
#define KSEL   64
#define BM 128
#define BN 128
#define BK 64
#define MTILES (TOKENS / BM)                       // 32
// pass A (sample)
#define NSPLIT_A 8
#define COLS_A   256                               // sample = first 2048 cols
#define SAMPLE_END (NSPLIT_A * COLS_A)             // 2048
// pass B (filter) over cols [SAMPLE_END, VOCAB)
#define NSPLIT_B 24
#define COLS_B (VOCAB - SAMPLE_END)                // 48209
#define COLS_PER ((COLS_B + NSPLIT_B - 1) / NSPLIT_B)  // 2009
#define GCAP 4096
#define CAP 56
#define MERGE_THR 17
#define TSZ (BM * BK)                              // 8192 B per fp8 tile buf
#define INF __builtin_inff()

typedef unsigned short u16;
typedef long i64;
typedef __attribute__((ext_vector_type(4))) float f32x4;

#define GLOAD16(gp, lp) __builtin_amdgcn_global_load_lds( \
    (const __attribute__((address_space(1))) void*)(gp),  \
    (__attribute__((address_space(3))) void*)(lp), 16, 0, 0)
#define GLOAD4(gp, lp) __builtin_amdgcn_global_load_lds(  \
    (const __attribute__((address_space(1))) void*)(gp),  \
    (__attribute__((address_space(3))) void*)(lp), 4, 0, 0)

// counted-vmcnt barrier: keep younger staging loads in flight (T3/T4)
#define WAITB(N) do { asm volatile("s_waitcnt vmcnt(" #N ")" ::: "memory"); \
                      __builtin_amdgcn_s_barrier(); } while (0)
// LDS-visibility-only barrier: does NOT drain vmcnt
#define LBAR() do { asm volatile("s_waitcnt lgkmcnt(0)" ::: "memory"); \
                    __builtin_amdgcn_s_barrier(); } while (0)

// ---------------------------------------------------------------------------
// Kernel 1: x,b -> fp8 e4m3 + fp32 squared norms; zero gcnt. 1 block/row.
// ---------------------------------------------------------------------------
__global__ __launch_bounds__(256) void prep_kernel(
    const float* __restrict__ x, const float* __restrict__ b,
    uint8_t* __restrict__ xh, uint8_t* __restrict__ bh,
    float* __restrict__ xsq, float* __restrict__ bsq,
    int* __restrict__ gcnt) {
  int row = blockIdx.x;
  int tid = threadIdx.x;
  const float* src;
  uint8_t* dst;
  float* nrm;
  int r;
  if (row < TOKENS) {
    r = row; src = x + (size_t)r * DMODEL; dst = xh + (size_t)r * DMODEL; nrm = xsq;
    if (tid == 0) gcnt[r] = 0;
  } else {
    r = row - TOKENS; src = b + (size_t)r * DMODEL; dst = bh + (size_t)r * DMODEL; nrm = bsq;
  }
  float4 v = reinterpret_cast<const float4*>(src)[tid];
  float s = v.x * v.x + v.y * v.y + v.z * v.z + v.w * v.w;
  uint32_t w = __builtin_amdgcn_cvt_pk_fp8_f32(v.x, v.y, 0, false);
  w = __builtin_amdgcn_cvt_pk_fp8_f32(v.z, v.w, w, true);
  reinterpret_cast<uint32_t*>(dst)[tid] = w;
#pragma unroll
  for (int j = 1; j < 64; j <<= 1) s += __shfl_xor(s, j);
  __shared__ float acc4[4];
  if ((tid & 63) == 0) acc4[tid >> 6] = s;
  __syncthreads();
  if (tid == 0) nrm[r] = acc4[0] + acc4[1] + acc4[2] + acc4[3];
}

// ---------------------------------------------------------------------------
// merge_row: sort <=64 candidates (asc), merge 64 smallest into sorted lstv.
// ---------------------------------------------------------------------------
__device__ __attribute__((noinline)) float merge_row(float lstv, const float* cb, int cnt) {
  const int lane = threadIdx.x & 63;
  float v0 = (lane < cnt) ? cb[lane] : INF;
#pragma unroll
  for (int k = 2; k <= 64; k <<= 1) {
#pragma unroll
    for (int j = k >> 1; j > 0; j >>= 1) {
      float p = __shfl_xor(v0, j);
      bool keepmin = (((lane & j) == 0) == ((lane & k) == 0));
      v0 = keepmin ? fminf(v0, p) : fmaxf(v0, p);
    }
  }
  float rev = __shfl(v0, 63 - lane);
  float m = fminf(lstv, rev);
#pragma unroll
  for (int j = 32; j > 0; j >>= 1) {
    float p = __shfl_xor(m, j);
    m = ((lane & j) == 0) ? fminf(m, p) : fmaxf(m, p);
  }
  return m;
}

// merge64: both sorted asc across 64 lanes -> sorted asc 64 smallest of union
__device__ __forceinline__ float merge64(float a, float b, int lane) {
  float rev = __shfl(b, 63 - lane);
  float m = fminf(a, rev);
#pragma unroll
  for (int j = 32; j > 0; j >>= 1) {
    float p = __shfl_xor(m, j);
    m = ((lane & j) == 0) ? fminf(m, p) : fmaxf(m, p);
  }
  return m;
}

// ===========================================================================
// Shared GEMM machinery (fp8, 128x128 tile, BK=64, triple-buffer, vmcnt(2))
// ===========================================================================
#define STAGE_STEP(BB, KS) do {                        \
    GLOAD16(a_src + (KS), &As[(BB) + wave * 1024]);    \
    GLOAD16(b_src + (KS), &Bs[(BB) + wave * 1024]);    \
  } while (0)

#define MFMA8(a0_, a1_, b0_, b1_, b2_, b3_)                                           \
    acc[0][0] = __builtin_amdgcn_mfma_f32_16x16x32_fp8_fp8(a0_, b0_, acc[0][0], 0, 0, 0); \
    acc[0][1] = __builtin_amdgcn_mfma_f32_16x16x32_fp8_fp8(a0_, b1_, acc[0][1], 0, 0, 0); \
    acc[0][2] = __builtin_amdgcn_mfma_f32_16x16x32_fp8_fp8(a0_, b2_, acc[0][2], 0, 0, 0); \
    acc[0][3] = __builtin_amdgcn_mfma_f32_16x16x32_fp8_fp8(a0_, b3_, acc[0][3], 0, 0, 0); \
    acc[1][0] = __builtin_amdgcn_mfma_f32_16x16x32_fp8_fp8(a1_, b0_, acc[1][0], 0, 0, 0); \
    acc[1][1] = __builtin_amdgcn_mfma_f32_16x16x32_fp8_fp8(a1_, b1_, acc[1][1], 0, 0, 0); \
    acc[1][2] = __builtin_amdgcn_mfma_f32_16x16x32_fp8_fp8(a1_, b2_, acc[1][2], 0, 0, 0); \
    acc[1][3] = __builtin_amdgcn_mfma_f32_16x16x32_fp8_fp8(a1_, b3_, acc[1][3], 0, 0, 0);

#define LD8(arr, BB, off) (*reinterpret_cast<const i64*>(&(arr)[(BB) + (off)]))
#define COMPUTE_STEP(BB) do {                                                  \
    i64 a0 = LD8(As, BB, A00), a1 = LD8(As, BB, A10);                          \
    i64 b0 = LD8(Bs, BB, B00), b1 = LD8(Bs, BB, B10);                          \
    i64 b2 = LD8(Bs, BB, B20), b3 = LD8(Bs, BB, B30);                          \
    __builtin_amdgcn_s_setprio(1);                                             \
    MFMA8(a0, a1, b0, b1, b2, b3)                                              \
    __builtin_amdgcn_s_setprio(0);                                             \
    i64 a0b = LD8(As, BB, A01), a1b = LD8(As, BB, A11);                        \
    i64 b0b = LD8(Bs, BB, B01), b1b = LD8(Bs, BB, B11);                        \
    i64 b2b = LD8(Bs, BB, B21), b3b = LD8(Bs, BB, B31);                        \
    __builtin_amdgcn_s_setprio(1);                                             \
    MFMA8(a0b, a1b, b0b, b1b, b2b, b3b)                                        \
    __builtin_amdgcn_s_setprio(0);                                             \
  } while (0)

// frag/staging geometry (XOR-16B swizzle, same derivation as round 7)
#define GEOM_COMMON                                                            \
  const int g4 = lane >> 4, fr = lane & 15;                                    \
  const int wm = wave >> 1, wn = wave & 1;                                     \
  const int rj = g4 * 4;                                                       \
  auto po = [&](int row, int c) {                                              \
    return row * 64 + ((((c >> 4) ^ ((row >> 1) & 3)) << 4) | (c & 15));       \
  };                                                                           \
  const int c0 = g4 * 8, c1 = 32 + g4 * 8;                                     \
  const int rA0 = wm * 32 + fr, rA1 = rA0 + 16;                                \
  const int rB0 = wn * 64 + fr, rB1 = rB0 + 16, rB2 = rB0 + 32, rB3 = rB0 + 48;\
  const int A00 = po(rA0, c0), A01 = po(rA0, c1);                              \
  const int A10 = po(rA1, c0), A11 = po(rA1, c1);                              \
  const int B00 = po(rB0, c0), B01 = po(rB0, c1);                              \
  const int B10 = po(rB1, c0), B11 = po(rB1, c1);                              \
  const int B20 = po(rB2, c0), B21 = po(rB2, c1);                              \
  const int B30 = po(rB3, c0), B31 = po(rB3, c1);

// 16-step K pipeline (prologue S0,S1 staged; 2 steps in flight; WAR-safe)
#define K_PIPELINE()                                                            \
    _Pragma("unroll 1")                                                         \
    for (int i = 0; i < 4; ++i) {                                               \
      const int ksb = i * 192;                                                  \
      WAITB(2); STAGE_STEP(2 * TSZ, ksb + 128); COMPUTE_STEP(0);                \
      WAITB(2); STAGE_STEP(0,       ksb + 192); COMPUTE_STEP(TSZ);              \
      WAITB(2); STAGE_STEP(TSZ,     ksb + 256); COMPUTE_STEP(2 * TSZ);          \
    }                                                                           \
    WAITB(2); STAGE_STEP(2 * TSZ, 896); COMPUTE_STEP(0);                        \
    WAITB(2); STAGE_STEP(0,       960); COMPUTE_STEP(TSZ);                      \
    WAITB(2);                           COMPUTE_STEP(2 * TSZ);                  \
    WAITB(0);                           COMPUTE_STEP(0);

// ---------------------------------------------------------------------------
// Kernel 2 (pass A): fused GEMM + exact streaming top-64 over the SAMPLE
// (cols [0, 2048), 8 splits x 256 cols, 256 blocks).
// ---------------------------------------------------------------------------
__global__ __launch_bounds__(512, 4) void gemm_topk_sample(
    const uint8_t* __restrict__ xh, const uint8_t* __restrict__ bh,
    const float* __restrict__ xsq, const float* __restrict__ bsqg,
    float* __restrict__ parts) {
  __shared__ uint8_t As[3 * TSZ];
  __shared__ uint8_t Bs[3 * TSZ];
  __shared__ float cbuf[BM][CAP];
  __shared__ float tau[BM];
  __shared__ int   ccnt[BM];
  __shared__ float xsq_s[BM];

  const int tid  = threadIdx.x;
  const int lane = tid & 63;
  const int wave = tid >> 6;
  const int bid  = (blockIdx.x & 7) * 32 + (blockIdx.x >> 3);  // 256 = 8x32
  const int mt   = bid & (MTILES - 1);
  const int ns   = bid >> 5;

  const int mrow0 = mt * BM;
  const int col0  = ns * COLS_A;
  const int col1  = col0 + COLS_A;                  // <= 2048 < VOCAB
  const int nchunk = (COLS_A + BN - 1) / BN;        // 2

  const int stg_row = wave * 16 + (lane >> 2);
  const int stg_gran = ((lane & 3) ^ ((lane >> 3) & 3)) << 4;
  const uint8_t* a_src = xh + (size_t)(mrow0 + stg_row) * DMODEL + stg_gran;
  const uint8_t* b_src = bh + (size_t)(col0 + stg_row) * DMODEL + stg_gran;

  if (tid < BM) {
    xsq_s[tid] = xsq[mrow0 + tid];
    tau[tid] = INF;
    ccnt[tid] = 0;
  }
  STAGE_STEP(0, 0);
  STAGE_STEP(TSZ, BK);

  float lst[16];
#pragma unroll
  for (int i = 0; i < 16; ++i) lst[i] = INF;

  GEOM_COMMON
  const int r0 = wm * 32 + wn * 16;

#pragma unroll 1
  for (int ch = 0; ch < nchunk; ++ch) {
    const int cbase = col0 + ch * BN;
    f32x4 acc[2][4];
#pragma unroll
    for (int i = 0; i < 2; ++i)
#pragma unroll
      for (int j = 0; j < 4; ++j) acc[i][j] = (f32x4){0.f, 0.f, 0.f, 0.f};

    K_PIPELINE()

    const bool lastch = (ch == nchunk - 1);
#pragma unroll
    for (int p = 0; p < 4; ++p) {
      if (wn == (p & 1)) {
#pragma unroll
        for (int f2 = 0; f2 < 2; ++f2) {
          const int fn = (p >> 1) * 2 + f2;
          const int c = cbase + wn * 64 + fn * 16 + fr;
          const bool cv = (c < col1);
          const float bq = cv ? bsqg[c] : 0.f;
#pragma unroll
          for (int fm = 0; fm < 2; ++fm) {
#pragma unroll
            for (int j = 0; j < 4; ++j) {
              const int rl = wm * 32 + fm * 16 + rj + j;
              const float dist = xsq_s[rl] + bq - 2.0f * acc[fm][fn][j];
              if (cv && dist < tau[rl]) {
                int ix = atomicAdd(&ccnt[rl], 1);
                if (ix < CAP) cbuf[rl][ix] = dist;
              }
            }
          }
        }
      }
      LBAR();
      if (p == 0 && !lastch) {
        int gcn = cbase + BN + stg_row;
        if (gcn > VOCAB - 1) gcn = VOCAB - 1;
        b_src = bh + (size_t)gcn * DMODEL + stg_gran;
        STAGE_STEP(0, 0);
        STAGE_STEP(TSZ, BK);
      }
      const bool force = lastch && (p == 3);
#pragma unroll
      for (int rl16 = 0; rl16 < 16; ++rl16) {
        const int r = r0 + rl16;
        const int cnt = ccnt[r];
        if (cnt >= MERGE_THR || (force && cnt > 0)) {
          float m = merge_row(lst[rl16], &cbuf[r][0], cnt);
          lst[rl16] = m;
          if (lane == 63) { tau[r] = m; ccnt[r] = 0; }
        }
      }
      LBAR();
    }
  }

#pragma unroll
  for (int rl16 = 0; rl16 < 16; ++rl16) {
    parts[(size_t)(mrow0 + r0 + rl16) * (NSPLIT_A * KSEL) + ns * KSEL + lane] = lst[rl16];
  }
}

// ---------------------------------------------------------------------------
// Kernel 3: sample64[r][0..63] = sorted top-64 of sample (merge 8 lists).
// ---------------------------------------------------------------------------
__global__ __launch_bounds__(256) void tau_reduce_kernel(
    const float* __restrict__ parts, float* __restrict__ sample64) {
  const int lane = threadIdx.x & 63;
  const int row = blockIdx.x * 4 + (threadIdx.x >> 6);
  float v[8];
#pragma unroll
  for (int i = 0; i < 8; ++i)
    v[i] = parts[(size_t)row * (NSPLIT_A * KSEL) + i * KSEL + lane];
#pragma unroll
  for (int i = 0; i < 4; ++i) v[i] = merge64(v[i], v[i + 4], lane);
#pragma unroll
  for (int i = 0; i < 2; ++i) v[i] = merge64(v[i], v[i + 2], lane);
  v[0] = merge64(v[0], v[1], lane);
  sample64[(size_t)row * KSEL + lane] = v[0];
}

// ---------------------------------------------------------------------------
// Kernel 4 (pass B): PURE fp8 GEMM over cols [2048, VOCAB); epilogue appends
// dist < tau0 (= sample64[r][63]) to per-row global candidate lists.
// 768 blocks = 3 blocks/CU (LDS ~50.5KB).
// ---------------------------------------------------------------------------
__global__ __launch_bounds__(512, 4) void gemm_filter_kernel(
    const uint8_t* __restrict__ xh, const uint8_t* __restrict__ bh,
    const float* __restrict__ xsq, const float* __restrict__ bsqg,
    const float* __restrict__ sample64,
    float* __restrict__ gcand, int* __restrict__ gcnt) {
  __shared__ uint8_t As[3 * TSZ];    // 24KB
  __shared__ uint8_t Bs[3 * TSZ];    // 24KB
  __shared__ float bsq_s[2][BN];     // 1KB (parity by chunk)
  __shared__ float xsq_s[BM];
  __shared__ float tau_s[BM];
  // ~50.5KB -> 3 blocks/CU

  const int tid  = threadIdx.x;
  const int lane = tid & 63;
  const int wave = tid >> 6;
  const int bid  = (blockIdx.x & 7) * 96 + (blockIdx.x >> 3);  // 768 = 8x96
  const int mt   = bid & (MTILES - 1);
  const int ns   = bid >> 5;                                   // 0..23

  const int mrow0 = mt * BM;
  const int col0  = SAMPLE_END + ns * COLS_PER;
  const int col1  = (col0 + COLS_PER < VOCAB) ? (col0 + COLS_PER) : VOCAB;
  const int nchunk = (col1 - col0 + BN - 1) / BN;

  const int stg_row = wave * 16 + (lane >> 2);
  const int stg_gran = ((lane & 3) ^ ((lane >> 3) & 3)) << 4;
  const uint8_t* a_src = xh + (size_t)(mrow0 + stg_row) * DMODEL + stg_gran;
  int gc0 = col0 + stg_row; if (gc0 > VOCAB - 1) gc0 = VOCAB - 1;
  const uint8_t* b_src = bh + (size_t)gc0 * DMODEL + stg_gran;

#define STAGE_BSQ(CC) do {                                              \
    int c_ = col0 + (CC) * BN + lane;                                   \
    int cA_ = (c_ < VOCAB) ? c_ : (VOCAB - 1);                          \
    int cB_ = (c_ + 64 < VOCAB) ? (c_ + 64) : (VOCAB - 1);              \
    GLOAD4(bsqg + cA_, &bsq_s[(CC) & 1][0]);                            \
    GLOAD4(bsqg + cB_, &bsq_s[(CC) & 1][64]);                           \
  } while (0)

  if (tid < BM) {                     // plain loads before counted staging
    xsq_s[tid] = xsq[mrow0 + tid];
    tau_s[tid] = sample64[(size_t)(mrow0 + tid) * KSEL + (KSEL - 1)];
  }
  STAGE_BSQ(0);
  STAGE_STEP(0, 0);
  STAGE_STEP(TSZ, BK);

  GEOM_COMMON

#pragma unroll 1
  for (int ch = 0; ch < nchunk; ++ch) {
    const int cbase = col0 + ch * BN;
    f32x4 acc[2][4];
#pragma unroll
    for (int i = 0; i < 2; ++i)
#pragma unroll
      for (int j = 0; j < 4; ++j) acc[i][j] = (f32x4){0.f, 0.f, 0.f, 0.f};

    K_PIPELINE()

    const bool lastch = (ch == nchunk - 1);
    LBAR();                           // all buf0/buf1 ds_reads retired
    if (!lastch) {                    // next-chunk prologue; latency hides
      STAGE_BSQ(ch + 1);              // under the filter epilogue below
      int gcn = cbase + BN + stg_row;
      if (gcn > VOCAB - 1) gcn = VOCAB - 1;
      b_src = bh + (size_t)gcn * DMODEL + stg_gran;
      STAGE_STEP(0, 0);
      STAGE_STEP(TSZ, BK);
    }

    // ---- filter epilogue: dist < tau0 -> append to global candidates ----
#pragma unroll
    for (int fn = 0; fn < 4; ++fn) {
      const int c = cbase + wn * 64 + fn * 16 + fr;
      const bool cv = (c < col1);
      const float bq = bsq_s[ch & 1][wn * 64 + fn * 16 + fr];
#pragma unroll
      for (int fm = 0; fm < 2; ++fm) {
#pragma unroll
        for (int j = 0; j < 4; ++j) {
          const int rl = wm * 32 + fm * 16 + rj + j;
          const float dist = xsq_s[rl] + bq - 2.0f * acc[fm][fn][j];
          if (cv && dist < tau_s[rl]) {
            int ix = atomicAdd(&gcnt[mrow0 + rl], 1);
            if (ix < GCAP) gcand[(size_t)(mrow0 + rl) * GCAP + ix] = dist;
          }
        }
      }
    }
    // no trailing barrier: next chunk's first WAITB(2) rendezvous suffices
  }
}

// ---------------------------------------------------------------------------
// Kernel 5 (pass C): per row, top-64 = sample64 merged with all survivors.
// One wave per row.
// ---------------------------------------------------------------------------
__global__ __launch_bounds__(256) void select_kernel(
    const float* __restrict__ gcand, const int* __restrict__ gcnt,
    const float* __restrict__ sample64, float* __restrict__ out) {
  const int lane = threadIdx.x & 63;
  const int row = blockIdx.x * 4 + (threadIdx.x >> 6);
  int cnt = gcnt[row]; if (cnt > GCAP) cnt = GCAP;
  const float* src = gcand + (size_t)row * GCAP;
  float lst = sample64[(size_t)row * KSEL + lane];   // sorted asc
#pragma unroll 1
  for (int base = 0; base < cnt; base += 64) {
    int n = cnt - base; if (n > 64) n = 64;
    lst = merge_row(lst, src + base, n);
  }
  out[(size_t)row * KSEL + lane] = lst;
}

// ---------------------------------------------------------------------------
extern "C" void kernel_launch(void* const* d_in, const int* in_sizes, int n_in,
                              void* d_out, int out_size, void* d_ws, size_t ws_size,
                              hipStream_t stream) {
  const float* x = (const float*)d_in[0];
  const float* b = (const float*)d_in[1];
  // d_in[2] = target (unused), d_in[3] = k (hardcoded 64)
  float* out = (float*)d_out;
  char* ws = (char*)d_ws;

  size_t off = 0;
  uint8_t* xh = (uint8_t*)(ws + off); off += (size_t)TOKENS * DMODEL;          // 4.2 MB
  uint8_t* bh = (uint8_t*)(ws + off); off += (size_t)VOCAB * DMODEL;           // 51.5 MB
  off = (off + 255) & ~(size_t)255;
  float* xsq = (float*)(ws + off); off += (size_t)TOKENS * sizeof(float);
  float* bsq = (float*)(ws + off); off += (((size_t)VOCAB * sizeof(float)) + 255) & ~(size_t)255;
  float* sample64 = (float*)(ws + off); off += (size_t)TOKENS * KSEL * sizeof(float); // 1 MB
  int* gcnt = (int*)(ws + off); off += (size_t)TOKENS * sizeof(int);
  float* parts = (float*)(ws + off); off += (size_t)TOKENS * NSPLIT_A * KSEL * sizeof(float); // 8.4 MB
  float* gcand = (float*)(ws + off); off += (size_t)TOKENS * GCAP * sizeof(float);            // 67 MB

  prep_kernel<<<TOKENS + VOCAB, 256, 0, stream>>>(x, b, xh, bh, xsq, bsq, gcnt);
  gemm_topk_sample<<<MTILES * NSPLIT_A, 512, 0, stream>>>(xh, bh, xsq, bsq, parts);
  tau_reduce_kernel<<<TOKENS / 4, 256, 0, stream>>>(parts, sample64);
  gemm_filter_kernel<<<MTILES * NSPLIT_B, 512, 0, stream>>>(xh, bh, xsq, bsq, sample64, gcand, gcnt);
  select_kernel<<<TOKENS / 4, 256, 0, stream>>>(gcand, gcnt, sample64, out);
}

// Round 10
// 612.594 us; speedup vs baseline: 1.7045x; 1.7045x over previous
//
#include <hip/hip_runtime.h>
#include <hip/hip_bf16.h>
#include <stdint.h>

#define TOKENS 4096
#define DMODEL 1024
#define VOCAB  50257
#define KSEL   64
#define BM 128
#define BN 128
#define BK 64
#define MTILES (TOKENS / BM)                       // 32
// pass A (sample): first 2048 cols, 16 splits x 128 cols, 512 blocks
#define NSPLIT_A 16
#define COLS_A   128
#define SAMPLE_END (NSPLIT_A * COLS_A)             // 2048
// pass B (filter) over cols [SAMPLE_END, VOCAB), 16 splits, 512 blocks
#define NSPLIT_B 16
#define COLS_B (VOCAB - SAMPLE_END)                // 48209
#define COLS_PER ((COLS_B + NSPLIT_B - 1) / NSPLIT_B)  // 3014
#define SEG 256                                    // per (block,row) survivor cap
#define CAP 56
#define MERGE_THR 17
#define TSZ (BM * BK)                              // 8192 B per fp8 tile buf
#define INF __builtin_inff()

typedef unsigned short u16;
typedef long i64;
typedef __attribute__((ext_vector_type(4))) float f32x4;

#define GLOAD16(gp, lp) __builtin_amdgcn_global_load_lds( \
    (const __attribute__((address_space(1))) void*)(gp),  \
    (__attribute__((address_space(3))) void*)(lp), 16, 0, 0)
#define GLOAD4(gp, lp) __builtin_amdgcn_global_load_lds(  \
    (const __attribute__((address_space(1))) void*)(gp),  \
    (__attribute__((address_space(3))) void*)(lp), 4, 0, 0)

// counted-vmcnt barrier: keep younger staging loads in flight (T3/T4)
#define WAITB(N) do { asm volatile("s_waitcnt vmcnt(" #N ")" ::: "memory"); \
                      __builtin_amdgcn_s_barrier(); } while (0)
// LDS-visibility-only barrier: does NOT drain vmcnt
#define LBAR() do { asm volatile("s_waitcnt lgkmcnt(0)" ::: "memory"); \
                    __builtin_amdgcn_s_barrier(); } while (0)
// drain outstanding stores (gfx9: stores count in vmcnt) without a barrier
#define DRAIN_VM() asm volatile("s_waitcnt vmcnt(0)" ::: "memory")

// ---------------------------------------------------------------------------
// Kernel 1: x,b -> fp8 e4m3 + fp32 squared norms. 1 block/row.
// ---------------------------------------------------------------------------
__global__ __launch_bounds__(256) void prep_kernel(
    const float* __restrict__ x, const float* __restrict__ b,
    uint8_t* __restrict__ xh, uint8_t* __restrict__ bh,
    float* __restrict__ xsq, float* __restrict__ bsq) {
  int row = blockIdx.x;
  int tid = threadIdx.x;
  const float* src;
  uint8_t* dst;
  float* nrm;
  int r;
  if (row < TOKENS) {
    r = row; src = x + (size_t)r * DMODEL; dst = xh + (size_t)r * DMODEL; nrm = xsq;
  } else {
    r = row - TOKENS; src = b + (size_t)r * DMODEL; dst = bh + (size_t)r * DMODEL; nrm = bsq;
  }
  float4 v = reinterpret_cast<const float4*>(src)[tid];
  float s = v.x * v.x + v.y * v.y + v.z * v.z + v.w * v.w;
  uint32_t w = __builtin_amdgcn_cvt_pk_fp8_f32(v.x, v.y, 0, false);
  w = __builtin_amdgcn_cvt_pk_fp8_f32(v.z, v.w, w, true);
  reinterpret_cast<uint32_t*>(dst)[tid] = w;
#pragma unroll
  for (int j = 1; j < 64; j <<= 1) s += __shfl_xor(s, j);
  __shared__ float acc4[4];
  if ((tid & 63) == 0) acc4[tid >> 6] = s;
  __syncthreads();
  if (tid == 0) nrm[r] = acc4[0] + acc4[1] + acc4[2] + acc4[3];
}

// ---------------------------------------------------------------------------
// merge_row: sort <=64 candidates (asc), merge 64 smallest into sorted lstv.
// ---------------------------------------------------------------------------
__device__ __attribute__((noinline)) float merge_row(float lstv, const float* cb, int cnt) {
  const int lane = threadIdx.x & 63;
  float v0 = (lane < cnt) ? cb[lane] : INF;
#pragma unroll
  for (int k = 2; k <= 64; k <<= 1) {
#pragma unroll
    for (int j = k >> 1; j > 0; j >>= 1) {
      float p = __shfl_xor(v0, j);
      bool keepmin = (((lane & j) == 0) == ((lane & k) == 0));
      v0 = keepmin ? fminf(v0, p) : fmaxf(v0, p);
    }
  }
  float rev = __shfl(v0, 63 - lane);
  float m = fminf(lstv, rev);
#pragma unroll
  for (int j = 32; j > 0; j >>= 1) {
    float p = __shfl_xor(m, j);
    m = ((lane & j) == 0) ? fminf(m, p) : fmaxf(m, p);
  }
  return m;
}

// merge64: both sorted asc across 64 lanes -> sorted asc 64 smallest of union
__device__ __forceinline__ float merge64(float a, float b, int lane) {
  float rev = __shfl(b, 63 - lane);
  float m = fminf(a, rev);
#pragma unroll
  for (int j = 32; j > 0; j >>= 1) {
    float p = __shfl_xor(m, j);
    m = ((lane & j) == 0) ? fminf(m, p) : fmaxf(m, p);
  }
  return m;
}

// ===========================================================================
// Shared GEMM machinery (fp8, 128x128 tile, BK=64)
// ===========================================================================
#define STAGE_STEP(BB, KS) do {                        \
    GLOAD16(a_src + (KS), &As[(BB) + wave * 1024]);    \
    GLOAD16(b_src + (KS), &Bs[(BB) + wave * 1024]);    \
  } while (0)

#define MFMA8(a0_, a1_, b0_, b1_, b2_, b3_)                                           \
    acc[0][0] = __builtin_amdgcn_mfma_f32_16x16x32_fp8_fp8(a0_, b0_, acc[0][0], 0, 0, 0); \
    acc[0][1] = __builtin_amdgcn_mfma_f32_16x16x32_fp8_fp8(a0_, b1_, acc[0][1], 0, 0, 0); \
    acc[0][2] = __builtin_amdgcn_mfma_f32_16x16x32_fp8_fp8(a0_, b2_, acc[0][2], 0, 0, 0); \
    acc[0][3] = __builtin_amdgcn_mfma_f32_16x16x32_fp8_fp8(a0_, b3_, acc[0][3], 0, 0, 0); \
    acc[1][0] = __builtin_amdgcn_mfma_f32_16x16x32_fp8_fp8(a1_, b0_, acc[1][0], 0, 0, 0); \
    acc[1][1] = __builtin_amdgcn_mfma_f32_16x16x32_fp8_fp8(a1_, b1_, acc[1][1], 0, 0, 0); \
    acc[1][2] = __builtin_amdgcn_mfma_f32_16x16x32_fp8_fp8(a1_, b2_, acc[1][2], 0, 0, 0); \
    acc[1][3] = __builtin_amdgcn_mfma_f32_16x16x32_fp8_fp8(a1_, b3_, acc[1][3], 0, 0, 0);

#define LD8(arr, BB, off) (*reinterpret_cast<const i64*>(&(arr)[(BB) + (off)]))
#define COMPUTE_STEP(BB) do {                                                  \
    i64 a0 = LD8(As, BB, A00), a1 = LD8(As, BB, A10);                          \
    i64 b0 = LD8(Bs, BB, B00), b1 = LD8(Bs, BB, B10);                          \
    i64 b2 = LD8(Bs, BB, B20), b3 = LD8(Bs, BB, B30);                          \
    __builtin_amdgcn_s_setprio(1);                                             \
    MFMA8(a0, a1, b0, b1, b2, b3)                                              \
    __builtin_amdgcn_s_setprio(0);                                             \
    i64 a0b = LD8(As, BB, A01), a1b = LD8(As, BB, A11);                        \
    i64 b0b = LD8(Bs, BB, B01), b1b = LD8(Bs, BB, B11);                        \
    i64 b2b = LD8(Bs, BB, B21), b3b = LD8(Bs, BB, B31);                        \
    __builtin_amdgcn_s_setprio(1);                                             \
    MFMA8(a0b, a1b, b0b, b1b, b2b, b3b)                                        \
    __builtin_amdgcn_s_setprio(0);                                             \
  } while (0)

// frag/staging geometry (XOR-16B swizzle)
#define GEOM_COMMON                                                            \
  const int g4 = lane >> 4, fr = lane & 15;                                    \
  const int wm = wave >> 1, wn = wave & 1;                                     \
  const int rj = g4 * 4;                                                       \
  auto po = [&](int row, int c) {                                              \
    return row * 64 + ((((c >> 4) ^ ((row >> 1) & 3)) << 4) | (c & 15));       \
  };                                                                           \
  const int c0 = g4 * 8, c1 = 32 + g4 * 8;                                     \
  const int rA0 = wm * 32 + fr, rA1 = rA0 + 16;                                \
  const int rB0 = wn * 64 + fr, rB1 = rB0 + 16, rB2 = rB0 + 32, rB3 = rB0 + 48;\
  const int A00 = po(rA0, c0), A01 = po(rA0, c1);                              \
  const int A10 = po(rA1, c0), A11 = po(rA1, c1);                              \
  const int B00 = po(rB0, c0), B01 = po(rB0, c1);                              \
  const int B10 = po(rB1, c0), B11 = po(rB1, c1);                              \
  const int B20 = po(rB2, c0), B21 = po(rB2, c1);                              \
  const int B30 = po(rB3, c0), B31 = po(rB3, c1);

// 3-buffer pipeline (2 steps in flight) — sample kernel (proven, round 8)
#define K_PIPELINE3()                                                           \
    _Pragma("unroll 1")                                                         \
    for (int i = 0; i < 4; ++i) {                                               \
      const int ksb = i * 192;                                                  \
      WAITB(2); STAGE_STEP(2 * TSZ, ksb + 128); COMPUTE_STEP(0);                \
      WAITB(2); STAGE_STEP(0,       ksb + 192); COMPUTE_STEP(TSZ);              \
      WAITB(2); STAGE_STEP(TSZ,     ksb + 256); COMPUTE_STEP(2 * TSZ);          \
    }                                                                           \
    WAITB(2); STAGE_STEP(2 * TSZ, 896); COMPUTE_STEP(0);                        \
    WAITB(2); STAGE_STEP(0,       960); COMPUTE_STEP(TSZ);                      \
    WAITB(2);                           COMPUTE_STEP(2 * TSZ);                  \
    WAITB(0);                           COMPUTE_STEP(0);

// 4-buffer pipeline (3 steps in flight) — filter kernel. Step t computes
// buf[t%4]; stage of S_{t+3} -> buf[(t+3)%4] = buf[(t-1)%4] is WAR-safe
// (barrier at top of step t means all waves finished compute t-1).
#define K_PIPELINE4()                                                           \
    _Pragma("unroll 1")                                                         \
    for (int i = 0; i < 3; ++i) {                                               \
      const int ksb = i * 256;                                                  \
      WAITB(4); STAGE_STEP(3 * TSZ, ksb + 192); COMPUTE_STEP(0);                \
      WAITB(4); STAGE_STEP(0,       ksb + 256); COMPUTE_STEP(TSZ);              \
      WAITB(4); STAGE_STEP(TSZ,     ksb + 320); COMPUTE_STEP(2 * TSZ);          \
      WAITB(4); STAGE_STEP(2 * TSZ, ksb + 384); COMPUTE_STEP(3 * TSZ);          \
    }                                                                           \
    WAITB(4); STAGE_STEP(3 * TSZ, 960); COMPUTE_STEP(0);      /* t=12 */        \
    WAITB(4);                           COMPUTE_STEP(TSZ);    /* t=13 */        \
    WAITB(2);                           COMPUTE_STEP(2 * TSZ);/* t=14 */        \
    WAITB(0);                           COMPUTE_STEP(3 * TSZ);/* t=15 */

// ---------------------------------------------------------------------------
// Kernel 2 (pass A): fused GEMM + exact streaming top-64 over the SAMPLE.
// 512 blocks (16 splits x 32 mtiles), 1 chunk each, 2 blocks/CU.
// ---------------------------------------------------------------------------
__global__ __launch_bounds__(512, 4) void gemm_topk_sample(
    const uint8_t* __restrict__ xh, const uint8_t* __restrict__ bh,
    const float* __restrict__ xsq, const float* __restrict__ bsqg,
    float* __restrict__ parts) {
  __shared__ uint8_t As[3 * TSZ];
  __shared__ uint8_t Bs[3 * TSZ];
  __shared__ float cbuf[BM][CAP];
  __shared__ float tau[BM];
  __shared__ int   ccnt[BM];
  __shared__ float xsq_s[BM];

  const int tid  = threadIdx.x;
  const int lane = tid & 63;
  const int wave = tid >> 6;
  // XCD-locality mapping: each XCD owns 4 mtiles (A L2-resident)
  const int xcd = blockIdx.x & 7, idx = blockIdx.x >> 3;
  const int mt  = xcd * 4 + (idx & 3);
  const int ns  = idx >> 2;                         // 0..15

  const int mrow0 = mt * BM;
  const int col0  = ns * COLS_A;
  const int col1  = col0 + COLS_A;                  // <= 2048

  const int stg_row = wave * 16 + (lane >> 2);
  const int stg_gran = ((lane & 3) ^ ((lane >> 3) & 3)) << 4;
  const uint8_t* a_src = xh + (size_t)(mrow0 + stg_row) * DMODEL + stg_gran;
  const uint8_t* b_src = bh + (size_t)(col0 + stg_row) * DMODEL + stg_gran;

  if (tid < BM) {
    xsq_s[tid] = xsq[mrow0 + tid];
    tau[tid] = INF;
    ccnt[tid] = 0;
  }
  STAGE_STEP(0, 0);
  STAGE_STEP(TSZ, BK);

  float lst[16];
#pragma unroll
  for (int i = 0; i < 16; ++i) lst[i] = INF;

  GEOM_COMMON
  const int r0 = wm * 32 + wn * 16;

  const int cbase = col0;
  f32x4 acc[2][4];
#pragma unroll
  for (int i = 0; i < 2; ++i)
#pragma unroll
    for (int j = 0; j < 4; ++j) acc[i][j] = (f32x4){0.f, 0.f, 0.f, 0.f};

  K_PIPELINE3()

  // 4 push/merge windows of 32 cols (ccnt growth <= 16+32 <= CAP)
#pragma unroll
  for (int p = 0; p < 4; ++p) {
    if (wn == (p & 1)) {
#pragma unroll
      for (int f2 = 0; f2 < 2; ++f2) {
        const int fn = (p >> 1) * 2 + f2;
        const int c = cbase + wn * 64 + fn * 16 + fr;
        const float bq = bsqg[c];
#pragma unroll
        for (int fm = 0; fm < 2; ++fm) {
#pragma unroll
          for (int j = 0; j < 4; ++j) {
            const int rl = wm * 32 + fm * 16 + rj + j;
            const float dist = xsq_s[rl] + bq - 2.0f * acc[fm][fn][j];
            if (dist < tau[rl]) {
              int ix = atomicAdd(&ccnt[rl], 1);
              if (ix < CAP) cbuf[rl][ix] = dist;
            }
          }
        }
      }
    }
    LBAR();
    const bool force = (p == 3);
#pragma unroll
    for (int rl16 = 0; rl16 < 16; ++rl16) {       // static idx (rule #20)
      const int r = r0 + rl16;
      const int cnt = ccnt[r];
      if (cnt >= MERGE_THR || (force && cnt > 0)) {
        float m = merge_row(lst[rl16], &cbuf[r][0], cnt);
        lst[rl16] = m;
        if (lane == 63) { tau[r] = m; ccnt[r] = 0; }
      }
    }
    LBAR();
  }

#pragma unroll
  for (int rl16 = 0; rl16 < 16; ++rl16) {
    parts[(size_t)(mrow0 + r0 + rl16) * (NSPLIT_A * KSEL) + ns * KSEL + lane] = lst[rl16];
  }
}

// ---------------------------------------------------------------------------
// Kernel 3: sample64[r][0..63] = sorted top-64 of sample (merge 16 lists).
// ---------------------------------------------------------------------------
__global__ __launch_bounds__(256) void tau_reduce_kernel(
    const float* __restrict__ parts, float* __restrict__ sample64) {
  const int lane = threadIdx.x & 63;
  const int row = blockIdx.x * 4 + (threadIdx.x >> 6);
  float v[16];
#pragma unroll
  for (int i = 0; i < 16; ++i)
    v[i] = parts[(size_t)row * (NSPLIT_A * KSEL) + i * KSEL + lane];
#pragma unroll
  for (int i = 0; i < 8; ++i) v[i] = merge64(v[i], v[i + 8], lane);
#pragma unroll
  for (int i = 0; i < 4; ++i) v[i] = merge64(v[i], v[i + 4], lane);
#pragma unroll
  for (int i = 0; i < 2; ++i) v[i] = merge64(v[i], v[i + 2], lane);
  v[0] = merge64(v[0], v[1], lane);
  sample64[(size_t)row * KSEL + lane] = v[0];
}

// ---------------------------------------------------------------------------
// Kernel 4 (pass B): PURE fp8 GEMM over cols [2048, VOCAB); survivors
// (dist < tau0) appended to per-(block,row) private segments via LDS
// counters — no global atomics. 512 blocks, 4-buf deep pipeline, 2/CU.
// ---------------------------------------------------------------------------
__global__ __launch_bounds__(512, 4) void gemm_filter_kernel(
    const uint8_t* __restrict__ xh, const uint8_t* __restrict__ bh,
    const float* __restrict__ xsq, const float* __restrict__ bsqg,
    const float* __restrict__ sample64,
    float* __restrict__ gcand, int* __restrict__ gcnt) {
  __shared__ uint8_t As[4 * TSZ];    // 32KB
  __shared__ uint8_t Bs[4 * TSZ];    // 32KB
  __shared__ float bsq_s[2][BN];     // 1KB (parity by chunk)
  __shared__ float xsq_s[BM];
  __shared__ float tau_s[BM];
  __shared__ int   svcnt[BM];        // per-row survivor counters (LDS atomics)
  // ~67KB -> 2 blocks/CU

  const int tid  = threadIdx.x;
  const int lane = tid & 63;
  const int wave = tid >> 6;
  // XCD-locality mapping: each XCD owns 4 mtiles -> A panel (512KB) L2-resident
  const int xcd = blockIdx.x & 7, idx = blockIdx.x >> 3;
  const int mt  = xcd * 4 + (idx & 3);
  const int ns  = idx >> 2;                         // 0..15

  const int mrow0 = mt * BM;
  const int col0  = SAMPLE_END + ns * COLS_PER;
  const int col1  = (col0 + COLS_PER < VOCAB) ? (col0 + COLS_PER) : VOCAB;
  const int nchunk = (col1 - col0 + BN - 1) / BN;

  const int stg_row = wave * 16 + (lane >> 2);
  const int stg_gran = ((lane & 3) ^ ((lane >> 3) & 3)) << 4;
  const uint8_t* a_src = xh + (size_t)(mrow0 + stg_row) * DMODEL + stg_gran;
  int gc0 = col0 + stg_row; if (gc0 > VOCAB - 1) gc0 = VOCAB - 1;
  const uint8_t* b_src = bh + (size_t)gc0 * DMODEL + stg_gran;

#define STAGE_BSQ(CC) do {                                              \
    int c_ = col0 + (CC) * BN + lane;                                   \
    int cA_ = (c_ < VOCAB) ? c_ : (VOCAB - 1);                          \
    int cB_ = (c_ + 64 < VOCAB) ? (c_ + 64) : (VOCAB - 1);              \
    GLOAD4(bsqg + cA_, &bsq_s[(CC) & 1][0]);                            \
    GLOAD4(bsqg + cB_, &bsq_s[(CC) & 1][64]);                           \
  } while (0)

  if (tid < BM) {                     // plain loads before counted staging
    xsq_s[tid] = xsq[mrow0 + tid];
    tau_s[tid] = sample64[(size_t)(mrow0 + tid) * KSEL + (KSEL - 1)];
    svcnt[tid] = 0;
  }
  // chunk-0 prologue: bsq + S0,S1,S2 (8 loads/wave in flight)
  STAGE_BSQ(0);
  STAGE_STEP(0, 0);
  STAGE_STEP(TSZ, BK);
  STAGE_STEP(2 * TSZ, 2 * BK);

  GEOM_COMMON
  float* seg_base = gcand + (size_t)mrow0 * (NSPLIT_B * SEG) + (size_t)ns * SEG;

#pragma unroll 1
  for (int ch = 0; ch < nchunk; ++ch) {
    const int cbase = col0 + ch * BN;
    f32x4 acc[2][4];
#pragma unroll
    for (int i = 0; i < 2; ++i)
#pragma unroll
      for (int j = 0; j < 4; ++j) acc[i][j] = (f32x4){0.f, 0.f, 0.f, 0.f};

    K_PIPELINE4()
    // WAITB(0) drained all loads; barrier passed -> tiles/bsq_s readable.

    // ---- filter epilogue: dist < tau0 -> LDS-counted private segment ----
#pragma unroll
    for (int fn = 0; fn < 4; ++fn) {
      const int c = cbase + wn * 64 + fn * 16 + fr;
      const bool cv = (c < col1);
      const float bq = bsq_s[ch & 1][wn * 64 + fn * 16 + fr];
#pragma unroll
      for (int fm = 0; fm < 2; ++fm) {
#pragma unroll
        for (int j = 0; j < 4; ++j) {
          const int rl = wm * 32 + fm * 16 + rj + j;
          const float dist = xsq_s[rl] + bq - 2.0f * acc[fm][fn][j];
          if (cv && dist < tau_s[rl]) {
            int ix = atomicAdd(&svcnt[rl], 1);       // LDS atomic (cheap)
            if (ix < SEG)
              seg_base[(size_t)rl * (NSPLIT_B * SEG) + ix] = dist;
          }
        }
      }
    }
    DRAIN_VM();                       // retire stores: keeps vmcnt ledger clean
    if (ch + 1 < nchunk) {            // next-chunk prologue (WAR-safe: all
      STAGE_BSQ(ch + 1);              // waves passed t=13/14/15 barriers)
      int gcn = cbase + BN + stg_row;
      if (gcn > VOCAB - 1) gcn = VOCAB - 1;
      b_src = bh + (size_t)gcn * DMODEL + stg_gran;
      STAGE_STEP(0, 0);
      STAGE_STEP(TSZ, BK);
      STAGE_STEP(2 * TSZ, 2 * BK);
    }
  }

  LBAR();                             // all LDS atomics visible
  if (tid < BM) {
    int c = svcnt[tid]; if (c > SEG) c = SEG;
    gcnt[(size_t)(mrow0 + tid) * NSPLIT_B + ns] = c;
  }
}

// ---------------------------------------------------------------------------
// Kernel 5 (pass C): per row, top-64 = sample64 merged with all survivors
// from the 16 per-block segments. One wave per row.
// ---------------------------------------------------------------------------
__global__ __launch_bounds__(256) void select_kernel(
    const float* __restrict__ gcand, const int* __restrict__ gcnt,
    const float* __restrict__ sample64, float* __restrict__ out) {
  const int lane = threadIdx.x & 63;
  const int row = blockIdx.x * 4 + (threadIdx.x >> 6);
  float lst = sample64[(size_t)row * KSEL + lane];   // sorted asc
#pragma unroll 1
  for (int s = 0; s < NSPLIT_B; ++s) {
    int cnt = gcnt[(size_t)row * NSPLIT_B + s];
    const float* src = gcand + (size_t)row * (NSPLIT_B * SEG) + (size_t)s * SEG;
#pragma unroll 1
    for (int base = 0; base < cnt; base += 64) {
      int n = cnt - base; if (n > 64) n = 64;
      lst = merge_row(lst, src + base, n);
    }
  }
  out[(size_t)row * KSEL + lane] = lst;
}

// ---------------------------------------------------------------------------
extern "C" void kernel_launch(void* const* d_in, const int* in_sizes, int n_in,
                              void* d_out, int out_size, void* d_ws, size_t ws_size,
                              hipStream_t stream) {
  const float* x = (const float*)d_in[0];
  const float* b = (const float*)d_in[1];
  // d_in[2] = target (unused), d_in[3] = k (hardcoded 64)
  float* out = (float*)d_out;
  char* ws = (char*)d_ws;

  size_t off = 0;
  uint8_t* xh = (uint8_t*)(ws + off); off += (size_t)TOKENS * DMODEL;          // 4.2 MB
  uint8_t* bh = (uint8_t*)(ws + off); off += (size_t)VOCAB * DMODEL;           // 51.5 MB
  off = (off + 255) & ~(size_t)255;
  float* xsq = (float*)(ws + off); off += (size_t)TOKENS * sizeof(float);
  float* bsq = (float*)(ws + off); off += (((size_t)VOCAB * sizeof(float)) + 255) & ~(size_t)255;
  float* sample64 = (float*)(ws + off); off += (size_t)TOKENS * KSEL * sizeof(float);      // 1 MB
  int* gcnt = (int*)(ws + off); off += (size_t)TOKENS * NSPLIT_B * sizeof(int);            // 256 KB
  float* parts = (float*)(ws + off); off += (size_t)TOKENS * NSPLIT_A * KSEL * sizeof(float); // 16.8 MB
  float* gcand = (float*)(ws + off); off += (size_t)TOKENS * NSPLIT_B * SEG * sizeof(float);  // 67 MB

  prep_kernel<<<TOKENS + VOCAB, 256, 0, stream>>>(x, b, xh, bh, xsq, bsq);
  gemm_topk_sample<<<MTILES * NSPLIT_A, 512, 0, stream>>>(xh, bh, xsq, bsq, parts);
  tau_reduce_kernel<<<TOKENS / 4, 256, 0, stream>>>(parts, sample64);
  gemm_filter_kernel<<<MTILES * NSPLIT_B, 512, 0, stream>>>(xh, bh, xsq, bsq, sample64, gcand, gcnt);
  select_kernel<<<TOKENS / 4, 256, 0, stream>>>(gcand, gcnt, sample64, out);
}